// Round 6
// baseline (693.187 us; speedup 1.0000x reference)
//
#include <hip/hip_runtime.h>
#include <hip/hip_bf16.h>

#define D 1024
#define KW 4
#define SEQL 8192
#define BATCH 4
#define MROWS (BATCH*SEQL)   // 32768
#define SEG 16
#define NSEG (SEQL/SEG)      // 512
#define NCHAIN (BATCH*D)     // 4096

using bf16 = __hip_bfloat16;
typedef __attribute__((ext_vector_type(8))) short bf16x8_t;   // 8 bf16 = 4 VGPR
typedef __attribute__((ext_vector_type(4))) float f32x4_t;

__device__ __forceinline__ float sigmoid_f(float x){ return 1.0f/(1.0f + __expf(-x)); }

__device__ __forceinline__ void gload_lds16(const bf16* g, bf16* l){
  __builtin_amdgcn_global_load_lds(
    (const __attribute__((address_space(1))) unsigned int*)g,
    (__attribute__((address_space(3))) unsigned int*)l,
    16, 0, 0);
}

__device__ __forceinline__ void bf16x2_unpack(unsigned int u, float& lo, float& hi){
  union { unsigned int i; float f; } a, b;
  a.i = (u & 0xffffu) << 16;
  b.i = u & 0xffff0000u;
  lo = a.f; hi = b.f;
}
__device__ __forceinline__ unsigned int bf16x2_pack(float lo, float hi){
  unsigned short l = __builtin_bit_cast(unsigned short, __float2bfloat16(lo));
  unsigned short h = __builtin_bit_cast(unsigned short, __float2bfloat16(hi));
  return (unsigned int)l | ((unsigned int)h << 16);
}

// ---------------- weight prep: fp32 -> bf16, concat [Wr;Wi] ----------------
__global__ __launch_bounds__(256) void prep_k(const float* __restrict__ Wr, const float* __restrict__ Wi,
                                              const float* __restrict__ Wrb, const float* __restrict__ Wib,
                                              const float* __restrict__ Wo,
                                              bf16* __restrict__ W1, bf16* __restrict__ Wob,
                                              float* __restrict__ b1){
  int idx = blockIdx.x*256 + threadIdx.x;
  if (idx < 2*D*D){
    int n = idx >> 10;
    float v = (n < D) ? Wr[idx] : Wi[idx - D*D];
    W1[idx] = __float2bfloat16(v);
  } else if (idx < 3*D*D){
    int j = idx - 2*D*D;
    Wob[j] = __float2bfloat16(Wo[j]);
  }
  if (idx < 2*D){
    b1[idx] = (idx < D) ? Wrb[idx] : Wib[idx - D];
  }
}

// ---------------- causal depthwise conv (4 ch x 2 rows / thread) ----------------
__global__ __launch_bounds__(256) void conv_k(const float* __restrict__ x, const float* __restrict__ w,
                                              const float* __restrict__ bias,
                                              unsigned int* __restrict__ xcb){   // bf16x2 pairs
  int idx = blockIdx.x*256 + threadIdx.x;   // (mm, c4), c4 in [0,256), mm in [0, MROWS/2)
  int c4 = idx & 255;
  int c  = c4 * 4;
  int mm = idx >> 8;
  int m  = mm * 2;                          // even; m+1 never crosses a batch boundary
  int l  = m & (SEQL-1);
  const float* wp = w + c*KW;               // 16 consecutive floats (4 channels x 4 taps)
  f32x4_t t0 = *(const f32x4_t*)(wp);
  f32x4_t t1 = *(const f32x4_t*)(wp + 4);
  f32x4_t t2 = *(const f32x4_t*)(wp + 8);
  f32x4_t t3 = *(const f32x4_t*)(wp + 12);
  f32x4_t bb = *(const f32x4_t*)(bias + c);
  const float* xm = x + (size_t)m*D + c;
  f32x4_t z  = (f32x4_t){0.f,0.f,0.f,0.f};
  f32x4_t r4 = *(const f32x4_t*)(xm + D);            // row m+1 (always valid)
  f32x4_t r3 = *(const f32x4_t*)(xm);                // row m
  f32x4_t r2 = (l>=1)? *(const f32x4_t*)(xm - D)   : z;
  f32x4_t r1 = (l>=2)? *(const f32x4_t*)(xm - 2*D) : z;
  f32x4_t r0 = (l>=3)? *(const f32x4_t*)(xm - 3*D) : z;
  // out(m):   taps over r0..r3 ; out(m+1): taps over r1..r4 (guards shared, see l>= above)
  float a0 = bb[0] + t0[0]*r0[0] + t0[1]*r1[0] + t0[2]*r2[0] + t0[3]*r3[0];
  float a1 = bb[1] + t1[0]*r0[1] + t1[1]*r1[1] + t1[2]*r2[1] + t1[3]*r3[1];
  float a2 = bb[2] + t2[0]*r0[2] + t2[1]*r1[2] + t2[2]*r2[2] + t2[3]*r3[2];
  float a3 = bb[3] + t3[0]*r0[3] + t3[1]*r1[3] + t3[2]*r2[3] + t3[3]*r3[3];
  float b0 = bb[0] + t0[0]*r1[0] + t0[1]*r2[0] + t0[2]*r3[0] + t0[3]*r4[0];
  float b1v= bb[1] + t1[0]*r1[1] + t1[1]*r2[1] + t1[2]*r3[1] + t1[3]*r4[1];
  float b2 = bb[2] + t2[0]*r1[2] + t2[1]*r2[2] + t2[2]*r3[2] + t2[3]*r4[2];
  float b3 = bb[3] + t3[0]*r1[3] + t3[1]*r2[3] + t3[2]*r3[3] + t3[3]*r4[3];
  uint2 o0, o1;
  o0.x = bf16x2_pack(a0, a1); o0.y = bf16x2_pack(a2, a3);
  o1.x = bf16x2_pack(b0, b1v); o1.y = bf16x2_pack(b2, b3);
  *(uint2*)(xcb + (size_t)m*512 + 2*c4)       = o0;
  *(uint2*)(xcb + (size_t)(m+1)*512 + 2*c4)   = o1;
}

// ---------------- 256x256 8-phase bf16 GEMM (m201 template) ----------------
// C[m,n] = sum_k A[m,k]*B[n,k] (+ bias[n]).  M,N % 256 == 0, K % 128 == 0, grid % 8 == 0.
template<typename OutT> __device__ __forceinline__ void store_cvt(OutT* p, float v);
template<> __device__ __forceinline__ void store_cvt<float>(float* p, float v){ *p = v; }
template<> __device__ __forceinline__ void store_cvt<bf16>(bf16* p, float v){ *p = __float2bfloat16(v); }

#define MFMA_BF16(a,b,c) __builtin_amdgcn_mfma_f32_16x16x32_bf16((a),(b),(c),0,0,0)

// Phase body: MFMAs ordered so each accumulator is reused at distance 8
// (k-slice 0 block, then k-slice 1 block) -- avoids dependent-pair pipe stalls.
#define GPHASE(buf, q, STAGE_STMT, WAIT_STMT) do{                         \
    bf16x8_t a0 = rdA(buf, 2*(q),   0);                                   \
    bf16x8_t a1 = rdA(buf, 2*(q),   1);                                   \
    bf16x8_t a2 = rdA(buf, 2*(q)+1, 0);                                   \
    bf16x8_t a3 = rdA(buf, 2*(q)+1, 1);                                   \
    if ((q) == 0){                                                        \
      b00 = rdB(buf,0,0); b01 = rdB(buf,0,1);                             \
      b10 = rdB(buf,1,0); b11 = rdB(buf,1,1);                             \
      b20 = rdB(buf,2,0); b21 = rdB(buf,2,1);                             \
      b30 = rdB(buf,3,0); b31 = rdB(buf,3,1);                             \
    }                                                                     \
    STAGE_STMT;                                                           \
    WAIT_STMT;                                                            \
    __builtin_amdgcn_s_barrier();                                         \
    asm volatile("s_waitcnt lgkmcnt(0)" ::: "memory");                    \
    __builtin_amdgcn_s_setprio(1);                                        \
    acc[2*(q)  ][0] = MFMA_BF16(a0, b00, acc[2*(q)  ][0]);                \
    acc[2*(q)  ][1] = MFMA_BF16(a0, b10, acc[2*(q)  ][1]);                \
    acc[2*(q)  ][2] = MFMA_BF16(a0, b20, acc[2*(q)  ][2]);                \
    acc[2*(q)  ][3] = MFMA_BF16(a0, b30, acc[2*(q)  ][3]);                \
    acc[2*(q)+1][0] = MFMA_BF16(a2, b00, acc[2*(q)+1][0]);                \
    acc[2*(q)+1][1] = MFMA_BF16(a2, b10, acc[2*(q)+1][1]);                \
    acc[2*(q)+1][2] = MFMA_BF16(a2, b20, acc[2*(q)+1][2]);                \
    acc[2*(q)+1][3] = MFMA_BF16(a2, b30, acc[2*(q)+1][3]);                \
    acc[2*(q)  ][0] = MFMA_BF16(a1, b01, acc[2*(q)  ][0]);                \
    acc[2*(q)  ][1] = MFMA_BF16(a1, b11, acc[2*(q)  ][1]);                \
    acc[2*(q)  ][2] = MFMA_BF16(a1, b21, acc[2*(q)  ][2]);                \
    acc[2*(q)  ][3] = MFMA_BF16(a1, b31, acc[2*(q)  ][3]);                \
    acc[2*(q)+1][0] = MFMA_BF16(a3, b01, acc[2*(q)+1][0]);                \
    acc[2*(q)+1][1] = MFMA_BF16(a3, b11, acc[2*(q)+1][1]);                \
    acc[2*(q)+1][2] = MFMA_BF16(a3, b21, acc[2*(q)+1][2]);                \
    acc[2*(q)+1][3] = MFMA_BF16(a3, b31, acc[2*(q)+1][3]);                \
    __builtin_amdgcn_s_setprio(0);                                        \
    __builtin_amdgcn_s_barrier();                                         \
}while(0)

#define WAIT_STEADY do{ if (it + 1 < nIter) asm volatile("s_waitcnt vmcnt(4)" ::: "memory"); \
                        else                asm volatile("s_waitcnt vmcnt(0)" ::: "memory"); }while(0)

template<typename OutT, bool HB>
__global__ __launch_bounds__(512, 2) void gemm256(const bf16* __restrict__ A, const bf16* __restrict__ B,
                                                  const float* __restrict__ bias, OutT* __restrict__ C,
                                                  int M, int N, int K){
  __shared__ alignas(128) bf16 Asm[2][256*64];   // 32 KB x2
  __shared__ alignas(128) bf16 Bsm[2][256*64];   // 32 KB x2  -> 128 KB total
  const int t    = threadIdx.x;
  const int wave = t >> 6, lane = t & 63;
  const int wm   = wave >> 2, wn = wave & 3;      // 2 x 4 wave grid; wave tile = 128x64
  const int lrow = lane & 15, quad = lane >> 4;

  // bijective XCD-aware block swizzle (gridDim.x % 8 == 0)
  const int nbn = N >> 8;
  const int cpx = gridDim.x >> 3;
  const int bid = blockIdx.x;
  const int swz = (bid & 7) * cpx + (bid >> 3);
  const int m0  = (swz / nbn) << 8;
  const int n0  = (swz % nbn) << 8;

  const int srow = wave*8 + (lane >> 3);                   // row within half (instr 0)
  const int scol = (((lane & 7) ^ (srow & 7)) << 3);       // swizzled source col (elements)

  auto stageA = [&](int tile, int half, int buf){
    const bf16* g = A + (size_t)(m0 + half*128 + srow)*K + tile*64 + scol;
    bf16* l = &Asm[buf][half*128*64 + wave*8*64];
    gload_lds16(g, l);
    gload_lds16(g + (size_t)64*K, l + 64*64);
  };
  auto stageB = [&](int tile, int half, int buf){
    const bf16* g = B + (size_t)(n0 + half*128 + srow)*K + tile*64 + scol;
    bf16* l = &Bsm[buf][half*128*64 + wave*8*64];
    gload_lds16(g, l);
    gload_lds16(g + (size_t)64*K, l + 64*64);
  };
  auto rdA = [&](int buf, int fi, int ks)->bf16x8_t{
    return *(const bf16x8_t*)&Asm[buf][(wm*128 + fi*16 + lrow)*64 + ((((ks)*4 + quad) ^ (lrow & 7)) << 3)];
  };
  auto rdB = [&](int buf, int j, int ks)->bf16x8_t{
    return *(const bf16x8_t*)&Bsm[buf][(wn*64 + j*16 + lrow)*64 + ((((ks)*4 + quad) ^ (lrow & 7)) << 3)];
  };

  f32x4_t acc[8][4];
  #pragma unroll
  for (int i=0;i<8;i++)
    #pragma unroll
    for (int j=0;j<4;j++) acc[i][j] = (f32x4_t){0.f,0.f,0.f,0.f};
  bf16x8_t b00,b01,b10,b11,b20,b21,b30,b31;

  const int nt    = K >> 6;    // K-tiles of 64
  const int nIter = nt >> 1;   // 2 tiles / iteration

  stageB(0, 0, 0); stageB(0, 1, 0);
  stageA(0, 0, 0); stageA(0, 1, 0);
  stageB(1, 0, 1); stageB(1, 1, 1);
  asm volatile("s_waitcnt vmcnt(4)" ::: "memory");
  __builtin_amdgcn_s_barrier();

  for (int it = 0; it < nIter; ++it){
    const int t1 = 2*it + 1, t2 = 2*it + 2, t3 = 2*it + 3;
    const bool ok2 = (t2 < nt), ok3 = (t3 < nt);
    GPHASE(0, 0, stageA(t1, 0, 1), );
    GPHASE(0, 1, stageA(t1, 1, 1), );
    GPHASE(0, 2, if (ok2) stageB(t2, 0, 0), );
    GPHASE(0, 3, if (ok2) stageB(t2, 1, 0), WAIT_STEADY);
    GPHASE(1, 0, if (ok2) stageA(t2, 0, 0), );
    GPHASE(1, 1, if (ok2) stageA(t2, 1, 0), );
    GPHASE(1, 2, if (ok3) stageB(t3, 0, 1), );
    GPHASE(1, 3, if (ok3) stageB(t3, 1, 1), WAIT_STEADY);
  }

  // ---- epilogue: LDS-staged coalesced C stores, padded rows (bank-conflict-free) ----
  constexpr int ROWP = 256 + 16/(int)sizeof(OutT);     // fp32: 260, bf16: 264 (stride in OutT)
  OutT* tile = (OutT*)&Asm[0][0];                      // 32 x ROWP OutT per step (fits 128KB LDS, all dead)
  const int trow = t >> 4;                             // 0..31
  const int tcol = (t & 15) * 16;                      // 16 OutT per thread per step
  float bvj[4];
  #pragma unroll
  for (int j=0;j<4;j++) bvj[j] = HB ? bias[n0 + wn*64 + j*16 + lrow] : 0.f;
  const int grow = m0 + (trow >> 4)*128 + (trow & 15);   // + i*16 per step

  #pragma unroll
  for (int i=0;i<8;i++){
    __builtin_amdgcn_s_barrier();                 // prev step's LDS reads done
    #pragma unroll
    for (int j=0;j<4;j++){
      int lcol = wn*64 + j*16 + lrow;
      #pragma unroll
      for (int r=0;r<4;r++)
        store_cvt(&tile[(wm*16 + quad*4 + r)*ROWP + lcol], acc[i][j][r] + bvj[j]);
    }
    __builtin_amdgcn_s_barrier();                 // writes visible
    const int4* lp = (const int4*)&tile[trow*ROWP + tcol];
    int4* gp = (int4*)&C[(size_t)(grow + i*16)*N + n0 + tcol];
    #pragma unroll
    for (int q=0; q<(int)sizeof(OutT); ++q) gp[q] = lp[q];   // fp32: 4x16B, bf16: 2x16B
  }
}

// ---------------- scan pass 1: segment-local (Aprod, Hend), 4 channels/thread ----------------
// Aprod/Hend stored TRANSPOSED: [s][b*D + c]  (coalesced f32x4 here, gathered in scan2)
__global__ __launch_bounds__(256) void scan1_k(const unsigned int* __restrict__ ri,    // bf16x2 [zr|zi]
                                               const unsigned int* __restrict__ xcb,   // bf16x2
                                               const float* __restrict__ log_a,
                                               float* __restrict__ AprodT, float* __restrict__ HendT){
  int idx = blockIdx.x*256 + threadIdx.x;       // (b, s, c4)
  int c4 = idx & 255;
  int c  = c4*4;
  int bs = idx >> 8;
  int s  = bs & (NSEG-1);
  int b  = bs >> 9;
  size_t m0 = (size_t)b*SEQL + (size_t)s*SEG;
  f32x4_t la = *(const f32x4_t*)(log_a + c);
  float c1[4];
  #pragma unroll
  for (int j=0;j<4;j++) c1[j] = -8.f * log1pf(__expf(-la[j]));   // 8*log(sigmoid(la))
  float A[4] = {1.f,1.f,1.f,1.f};
  float h[4] = {0.f,0.f,0.f,0.f};
  #pragma unroll 4
  for (int l=0; l<SEG; l++){
    size_t m = m0 + l;
    uint2 uzr = *(const uint2*)(ri  + m*1024 + 2*c4);
    uint2 uzi = *(const uint2*)(ri  + m*1024 + 512 + 2*c4);
    uint2 uxv = *(const uint2*)(xcb + m*512  + 2*c4);
    float zr[4], zi[4], xv[4];
    bf16x2_unpack(uzr.x, zr[0], zr[1]); bf16x2_unpack(uzr.y, zr[2], zr[3]);
    bf16x2_unpack(uzi.x, zi[0], zi[1]); bf16x2_unpack(uzi.y, zi[2], zi[3]);
    bf16x2_unpack(uxv.x, xv[0], xv[1]); bf16x2_unpack(uxv.y, xv[2], xv[3]);
    #pragma unroll
    for (int j=0;j<4;j++){
      float a  = __expf(c1[j] * sigmoid_f(zr[j]));
      float bt = sqrtf(fmaxf(1.f - a*a, 1e-6f)) * sigmoid_f(zi[j]) * xv[j];
      A[j] *= a;
      h[j]  = fmaf(a, h[j], bt);
    }
  }
  size_t tbase = (size_t)s*NCHAIN + (size_t)b*D + c;
  *(f32x4_t*)(AprodT + tbase) = (f32x4_t){A[0],A[1],A[2],A[3]};
  *(f32x4_t*)(HendT  + tbase) = (f32x4_t){h[0],h[1],h[2],h[3]};
}

// ---------------- scan pass 2: cross-segment carry, wave-parallel ----------------
// one 64-lane wave per chain (b,c); lane l folds segments [8l,8l+8), then Hillis-Steele
// wave scan with op (A1,H1)∘(A2,H2) = (A1*A2, A2*H1 + H2).
__global__ __launch_bounds__(256) void scan2_k(const float* __restrict__ AprodT, const float* __restrict__ HendT,
                                               float* __restrict__ carryT){
  int gid   = blockIdx.x*256 + threadIdx.x;
  int chain = gid >> 6;                       // 0..NCHAIN-1
  int lane  = gid & 63;
  int s0    = lane*8;
  float a[8], e[8];
  #pragma unroll
  for (int k=0;k<8;k++){
    a[k] = AprodT[(size_t)(s0+k)*NCHAIN + chain];
    e[k] = HendT [(size_t)(s0+k)*NCHAIN + chain];
  }
  float A = a[0], H = e[0];
  #pragma unroll
  for (int k=1;k<8;k++){ H = fmaf(a[k], H, e[k]); A *= a[k]; }
  #pragma unroll
  for (int off=1; off<64; off<<=1){
    float Ao = __shfl_up(A, off, 64);
    float Ho = __shfl_up(H, off, 64);
    if (lane >= off){ H = fmaf(A, Ho, H); A = A*Ao; }   // prev ∘ cur (H uses pre-update A)
  }
  float Hx = __shfl_up(H, 1, 64);           // exclusive prefix; initial h = 0
  if (lane == 0) Hx = 0.f;
  float h = Hx;
  #pragma unroll
  for (int k=0;k<8;k++){
    carryT[(size_t)(s0+k)*NCHAIN + chain] = h;
    h = fmaf(a[k], h, e[k]);
  }
}

// ---------------- scan pass 3: recompute + carry, emit h in-place over xcb (bf16x2) ----------------
__global__ __launch_bounds__(256) void scan3_k(const unsigned int* __restrict__ ri,
                                               unsigned int* xcb,            // read x_conv, write h in-place
                                               const float* __restrict__ log_a, const float* __restrict__ carryT){
  int idx = blockIdx.x*256 + threadIdx.x;       // (b, s, c4)
  int c4 = idx & 255;
  int c  = c4*4;
  int bs = idx >> 8;
  int s  = bs & (NSEG-1);
  int b  = bs >> 9;
  size_t m0 = (size_t)b*SEQL + (size_t)s*SEG;
  f32x4_t la = *(const f32x4_t*)(log_a + c);
  float c1[4];
  #pragma unroll
  for (int j=0;j<4;j++) c1[j] = -8.f * log1pf(__expf(-la[j]));
  f32x4_t h4 = *(const f32x4_t*)(carryT + (size_t)s*NCHAIN + (size_t)b*D + c);
  float h[4] = {h4[0], h4[1], h4[2], h4[3]};
  #pragma unroll 4
  for (int l=0; l<SEG; l++){
    size_t m = m0 + l;
    uint2 uzr = *(const uint2*)(ri  + m*1024 + 2*c4);
    uint2 uzi = *(const uint2*)(ri  + m*1024 + 512 + 2*c4);
    uint2 uxv = *(const uint2*)(xcb + m*512  + 2*c4);
    float zr[4], zi[4], xv[4];
    bf16x2_unpack(uzr.x, zr[0], zr[1]); bf16x2_unpack(uzr.y, zr[2], zr[3]);
    bf16x2_unpack(uzi.x, zi[0], zi[1]); bf16x2_unpack(uzi.y, zi[2], zi[3]);
    bf16x2_unpack(uxv.x, xv[0], xv[1]); bf16x2_unpack(uxv.y, xv[2], xv[3]);
    #pragma unroll
    for (int j=0;j<4;j++){
      float a  = __expf(c1[j] * sigmoid_f(zr[j]));
      float bt = sqrtf(fmaxf(1.f - a*a, 1e-6f)) * sigmoid_f(zi[j]) * xv[j];
      h[j] = fmaf(a, h[j], bt);
    }
    uint2 o;
    o.x = bf16x2_pack(h[0], h[1]);
    o.y = bf16x2_pack(h[2], h[3]);
    *(uint2*)(xcb + m*512 + 2*c4) = o;
  }
}

// ---------------- RMSNorm: wave-per-row, 4 rows/block, in-place ----------------
__global__ __launch_bounds__(256) void rms_k(float* __restrict__ y, const float* __restrict__ nw){
  int wave = threadIdx.x >> 6, lane = threadIdx.x & 63;
  size_t row = (size_t)blockIdx.x*4 + wave;
  float* yr = y + row*D;
  f32x4_t v[4];
  #pragma unroll
  for (int q=0;q<4;q++) v[q] = *(const f32x4_t*)(yr + q*256 + lane*4);
  float ss = 0.f;
  #pragma unroll
  for (int q=0;q<4;q++) ss += v[q][0]*v[q][0] + v[q][1]*v[q][1] + v[q][2]*v[q][2] + v[q][3]*v[q][3];
  #pragma unroll
  for (int off=32; off>0; off>>=1) ss += __shfl_xor(ss, off, 64);
  float scale = rsqrtf(ss * (1.f/D) + 1e-6f);
  #pragma unroll
  for (int q=0;q<4;q++){
    f32x4_t w = *(const f32x4_t*)(nw + q*256 + lane*4);
    f32x4_t o;
    #pragma unroll
    for (int k=0;k<4;k++) o[k] = v[q][k]*scale*w[k];
    *(f32x4_t*)(yr + q*256 + lane*4) = o;
  }
}

extern "C" void kernel_launch(void* const* d_in, const int* in_sizes, int n_in,
                              void* d_out, int out_size, void* d_ws, size_t ws_size,
                              hipStream_t stream) {
  const float* x     = (const float*)d_in[0];
  const float* convw = (const float*)d_in[1];
  const float* convb = (const float*)d_in[2];
  const float* Wr_w  = (const float*)d_in[3];
  const float* Wr_b  = (const float*)d_in[4];
  const float* Wi_w  = (const float*)d_in[5];
  const float* Wi_b  = (const float*)d_in[6];
  const float* log_a = (const float*)d_in[7];
  const float* out_w = (const float*)d_in[8];
  const float* norm_w= (const float*)d_in[9];

  char* ws = (char*)d_ws;
  size_t off = 0;
  auto alloc = [&](size_t bytes)->char*{ char* p = ws + off; off += (bytes + 255) & ~(size_t)255; return p; };

  bf16*  xcb   = (bf16*) alloc((size_t)MROWS*D*2);       // 64 MB, bf16 x_conv; scan3 overwrites with h
  bf16*  ri    = (bf16*) alloc((size_t)MROWS*2*D*2);     // 128 MB, raw logits [zr|zi]
  bf16*  W1    = (bf16*) alloc((size_t)2*D*D*2);         // 4 MB
  bf16*  Wob   = (bf16*) alloc((size_t)D*D*2);           // 2 MB
  float* b1    = (float*)alloc((size_t)2*D*4);
  float* AprodT= (float*)alloc((size_t)NSEG*NCHAIN*4);   // 8 MB, [s][chain]
  float* HendT = (float*)alloc((size_t)NSEG*NCHAIN*4);   // 8 MB
  float* carryT= (float*)alloc((size_t)NSEG*NCHAIN*4);   // 8 MB
  float* y     = (float*)d_out;                          // GEMM2 output, rmsnorm in-place

  // 1. weight prep
  prep_k<<<dim3((3*D*D + 255)/256), dim3(256), 0, stream>>>(Wr_w, Wi_w, Wr_b, Wi_b, out_w, W1, Wob, b1);
  // 2. conv -> bf16 only (4 ch x 2 rows / thread)
  conv_k<<<dim3((MROWS/2)*(D/4)/256), dim3(256), 0, stream>>>(x, convw, convb, (unsigned int*)xcb);
  // 3. GEMM1: raw logits + bias -> ri (bf16), N=2048  (sigmoid applied in scan)
  gemm256<bf16, true><<<dim3((MROWS/256)*((2*D)/256)), dim3(512), 0, stream>>>(xcb, W1, b1, ri, MROWS, 2*D, D);
  // 4-6. blocked scan (SEG=16, 4 channels/thread; wave-parallel carry)
  scan1_k<<<dim3(BATCH*NSEG*(D/4)/256), dim3(256), 0, stream>>>((const unsigned int*)ri, (const unsigned int*)xcb, log_a, AprodT, HendT);
  scan2_k<<<dim3(NCHAIN*64/256), dim3(256), 0, stream>>>(AprodT, HendT, carryT);
  scan3_k<<<dim3(BATCH*NSEG*(D/4)/256), dim3(256), 0, stream>>>((const unsigned int*)ri, (unsigned int*)xcb, log_a, carryT);
  // 7. GEMM2: y = h @ out_w^T (fp32 out, no bias); A = h written in-place over xcb
  gemm256<float, false><<<dim3((MROWS/256)*(D/256)), dim3(512), 0, stream>>>(xcb, Wob, nullptr, y, MROWS, D, D);
  // 8. RMSNorm in-place on d_out (wave per row)
  rms_k<<<dim3(MROWS/4), dim3(256), 0, stream>>>(y, norm_w);
}

// Round 7
// 657.806 us; speedup vs baseline: 1.0538x; 1.0538x over previous
//
#include <hip/hip_runtime.h>
#include <hip/hip_bf16.h>

#define D 1024
#define KW 4
#define SEQL 8192
#define BATCH 4
#define MROWS (BATCH*SEQL)   // 32768
#define SEG 32
#define NSEG (SEQL/SEG)      // 256
#define NCHAIN (BATCH*D)     // 4096

using bf16 = __hip_bfloat16;
typedef __attribute__((ext_vector_type(8))) short bf16x8_t;   // 8 bf16 = 4 VGPR
typedef __attribute__((ext_vector_type(4))) float f32x4_t;

__device__ __forceinline__ float sigmoid_f(float x){ return 1.0f/(1.0f + __expf(-x)); }

__device__ __forceinline__ void gload_lds16(const bf16* g, bf16* l){
  __builtin_amdgcn_global_load_lds(
    (const __attribute__((address_space(1))) unsigned int*)g,
    (__attribute__((address_space(3))) unsigned int*)l,
    16, 0, 0);
}

__device__ __forceinline__ void bf16x2_unpack(unsigned int u, float& lo, float& hi){
  union { unsigned int i; float f; } a, b;
  a.i = (u & 0xffffu) << 16;
  b.i = u & 0xffff0000u;
  lo = a.f; hi = b.f;
}
__device__ __forceinline__ unsigned int bf16x2_pack(float lo, float hi){
  unsigned short l = __builtin_bit_cast(unsigned short, __float2bfloat16(lo));
  unsigned short h = __builtin_bit_cast(unsigned short, __float2bfloat16(hi));
  return (unsigned int)l | ((unsigned int)h << 16);
}

// ---------------- weight prep: fp32 -> bf16, INTERLEAVED [Wr_c; Wi_c] rows; c1 table ----------------
__global__ __launch_bounds__(256) void prep_k(const float* __restrict__ Wr, const float* __restrict__ Wi,
                                              const float* __restrict__ Wrb, const float* __restrict__ Wib,
                                              const float* __restrict__ Wo, const float* __restrict__ log_a,
                                              bf16* __restrict__ W1, bf16* __restrict__ Wob,
                                              float* __restrict__ b1, float* __restrict__ c1buf){
  int idx = blockIdx.x*256 + threadIdx.x;
  if (idx < 2*D*D){
    int n   = idx >> 10;          // interleaved row: even = Wr[c], odd = Wi[c]
    int col = idx & 1023;
    int c   = n >> 1;
    float v = (n & 1) ? Wi[(size_t)c*D + col] : Wr[(size_t)c*D + col];
    W1[idx] = __float2bfloat16(v);
  } else if (idx < 3*D*D){
    int j = idx - 2*D*D;
    Wob[j] = __float2bfloat16(Wo[j]);
  }
  if (idx < 2*D){
    int c = idx >> 1;
    b1[idx] = (idx & 1) ? Wib[c] : Wrb[c];
  }
  if (idx < D){
    c1buf[idx] = -8.f * log1pf(__expf(-log_a[idx]));   // 8*log(sigmoid(log_a))
  }
}

// ---------------- causal depthwise conv (4 ch x 2 rows / thread) ----------------
__global__ __launch_bounds__(256) void conv_k(const float* __restrict__ x, const float* __restrict__ w,
                                              const float* __restrict__ bias,
                                              unsigned int* __restrict__ xcb){   // bf16x2 pairs
  int idx = blockIdx.x*256 + threadIdx.x;   // (mm, c4), c4 in [0,256), mm in [0, MROWS/2)
  int c4 = idx & 255;
  int c  = c4 * 4;
  int mm = idx >> 8;
  int m  = mm * 2;                          // even; m+1 never crosses a batch boundary
  int l  = m & (SEQL-1);
  const float* wp = w + c*KW;               // 16 consecutive floats (4 channels x 4 taps)
  f32x4_t t0 = *(const f32x4_t*)(wp);
  f32x4_t t1 = *(const f32x4_t*)(wp + 4);
  f32x4_t t2 = *(const f32x4_t*)(wp + 8);
  f32x4_t t3 = *(const f32x4_t*)(wp + 12);
  f32x4_t bb = *(const f32x4_t*)(bias + c);
  const float* xm = x + (size_t)m*D + c;
  f32x4_t z  = (f32x4_t){0.f,0.f,0.f,0.f};
  f32x4_t r4 = *(const f32x4_t*)(xm + D);            // row m+1 (always valid)
  f32x4_t r3 = *(const f32x4_t*)(xm);                // row m
  f32x4_t r2 = (l>=1)? *(const f32x4_t*)(xm - D)   : z;
  f32x4_t r1 = (l>=2)? *(const f32x4_t*)(xm - 2*D) : z;
  f32x4_t r0 = (l>=3)? *(const f32x4_t*)(xm - 3*D) : z;
  float a0 = bb[0] + t0[0]*r0[0] + t0[1]*r1[0] + t0[2]*r2[0] + t0[3]*r3[0];
  float a1 = bb[1] + t1[0]*r0[1] + t1[1]*r1[1] + t1[2]*r2[1] + t1[3]*r3[1];
  float a2 = bb[2] + t2[0]*r0[2] + t2[1]*r1[2] + t2[2]*r2[2] + t2[3]*r3[2];
  float a3 = bb[3] + t3[0]*r0[3] + t3[1]*r1[3] + t3[2]*r2[3] + t3[3]*r3[3];
  float b0 = bb[0] + t0[0]*r1[0] + t0[1]*r2[0] + t0[2]*r3[0] + t0[3]*r4[0];
  float b1v= bb[1] + t1[0]*r1[1] + t1[1]*r2[1] + t1[2]*r3[1] + t1[3]*r4[1];
  float b2 = bb[2] + t2[0]*r1[2] + t2[1]*r2[2] + t2[2]*r3[2] + t2[3]*r4[2];
  float b3 = bb[3] + t3[0]*r1[3] + t3[1]*r2[3] + t3[2]*r3[3] + t3[3]*r4[3];
  uint2 o0, o1;
  o0.x = bf16x2_pack(a0, a1); o0.y = bf16x2_pack(a2, a3);
  o1.x = bf16x2_pack(b0, b1v); o1.y = bf16x2_pack(b2, b3);
  *(uint2*)(xcb + (size_t)m*512 + 2*c4)       = o0;
  *(uint2*)(xcb + (size_t)(m+1)*512 + 2*c4)   = o1;
}

// ---------------- 256x256 8-phase bf16 GEMM (m201 template) ----------------
// C[m,n] = sum_k A[m,k]*B[n,k] (+ bias[n]).  M,N % 256 == 0, K % 128 == 0, grid % 8 == 0.
// FUSE: output columns hold interleaved (zr,zi) channel pairs; epilogue converts each
// pair to (d=1-a_t, b_t) bf16 using xv_src (x_conv) and c1buf, writing the scan's input.
template<typename OutT> __device__ __forceinline__ void store_cvt(OutT* p, float v);
template<> __device__ __forceinline__ void store_cvt<float>(float* p, float v){ *p = v; }
template<> __device__ __forceinline__ void store_cvt<bf16>(bf16* p, float v){ *p = __float2bfloat16(v); }

#define MFMA_BF16(a,b,c) __builtin_amdgcn_mfma_f32_16x16x32_bf16((a),(b),(c),0,0,0)

#define GPHASE(buf, q, STAGE_STMT, WAIT_STMT) do{                         \
    bf16x8_t a0 = rdA(buf, 2*(q),   0);                                   \
    bf16x8_t a1 = rdA(buf, 2*(q),   1);                                   \
    bf16x8_t a2 = rdA(buf, 2*(q)+1, 0);                                   \
    bf16x8_t a3 = rdA(buf, 2*(q)+1, 1);                                   \
    if ((q) == 0){                                                        \
      b00 = rdB(buf,0,0); b01 = rdB(buf,0,1);                             \
      b10 = rdB(buf,1,0); b11 = rdB(buf,1,1);                             \
      b20 = rdB(buf,2,0); b21 = rdB(buf,2,1);                             \
      b30 = rdB(buf,3,0); b31 = rdB(buf,3,1);                             \
    }                                                                     \
    STAGE_STMT;                                                           \
    WAIT_STMT;                                                            \
    __builtin_amdgcn_s_barrier();                                         \
    asm volatile("s_waitcnt lgkmcnt(0)" ::: "memory");                    \
    __builtin_amdgcn_s_setprio(1);                                        \
    acc[2*(q)  ][0] = MFMA_BF16(a0, b00, acc[2*(q)  ][0]);                \
    acc[2*(q)  ][1] = MFMA_BF16(a0, b10, acc[2*(q)  ][1]);                \
    acc[2*(q)  ][2] = MFMA_BF16(a0, b20, acc[2*(q)  ][2]);                \
    acc[2*(q)  ][3] = MFMA_BF16(a0, b30, acc[2*(q)  ][3]);                \
    acc[2*(q)+1][0] = MFMA_BF16(a2, b00, acc[2*(q)+1][0]);                \
    acc[2*(q)+1][1] = MFMA_BF16(a2, b10, acc[2*(q)+1][1]);                \
    acc[2*(q)+1][2] = MFMA_BF16(a2, b20, acc[2*(q)+1][2]);                \
    acc[2*(q)+1][3] = MFMA_BF16(a2, b30, acc[2*(q)+1][3]);                \
    acc[2*(q)  ][0] = MFMA_BF16(a1, b01, acc[2*(q)  ][0]);                \
    acc[2*(q)  ][1] = MFMA_BF16(a1, b11, acc[2*(q)  ][1]);                \
    acc[2*(q)  ][2] = MFMA_BF16(a1, b21, acc[2*(q)  ][2]);                \
    acc[2*(q)  ][3] = MFMA_BF16(a1, b31, acc[2*(q)  ][3]);                \
    acc[2*(q)+1][0] = MFMA_BF16(a3, b01, acc[2*(q)+1][0]);                \
    acc[2*(q)+1][1] = MFMA_BF16(a3, b11, acc[2*(q)+1][1]);                \
    acc[2*(q)+1][2] = MFMA_BF16(a3, b21, acc[2*(q)+1][2]);                \
    acc[2*(q)+1][3] = MFMA_BF16(a3, b31, acc[2*(q)+1][3]);                \
    __builtin_amdgcn_s_setprio(0);                                        \
    __builtin_amdgcn_s_barrier();                                         \
}while(0)

#define WAIT_STEADY do{ if (it + 1 < nIter) asm volatile("s_waitcnt vmcnt(4)" ::: "memory"); \
                        else                asm volatile("s_waitcnt vmcnt(0)" ::: "memory"); }while(0)

template<typename OutT, bool HB, bool FUSE>
__global__ __launch_bounds__(512, 2) void gemm256(const bf16* __restrict__ A, const bf16* __restrict__ B,
                                                  const float* __restrict__ bias, OutT* __restrict__ C,
                                                  int M, int N, int K,
                                                  const bf16* __restrict__ xv_src,
                                                  const float* __restrict__ c1buf){
  __shared__ alignas(128) bf16 Asm[2][256*64];   // 32 KB x2
  __shared__ alignas(128) bf16 Bsm[2][256*64];   // 32 KB x2  -> 128 KB total
  const int t    = threadIdx.x;
  const int wave = t >> 6, lane = t & 63;
  const int wm   = wave >> 2, wn = wave & 3;      // 2 x 4 wave grid; wave tile = 128x64
  const int lrow = lane & 15, quad = lane >> 4;

  // bijective XCD-aware block swizzle (gridDim.x % 8 == 0)
  const int nbn = N >> 8;
  const int cpx = gridDim.x >> 3;
  const int bid = blockIdx.x;
  const int swz = (bid & 7) * cpx + (bid >> 3);
  const int m0  = (swz / nbn) << 8;
  const int n0  = (swz % nbn) << 8;

  const int srow = wave*8 + (lane >> 3);                   // row within half (instr 0)
  const int scol = (((lane & 7) ^ (srow & 7)) << 3);       // swizzled source col (elements)

  auto stageA = [&](int tile, int half, int buf){
    const bf16* g = A + (size_t)(m0 + half*128 + srow)*K + tile*64 + scol;
    bf16* l = &Asm[buf][half*128*64 + wave*8*64];
    gload_lds16(g, l);
    gload_lds16(g + (size_t)64*K, l + 64*64);
  };
  auto stageB = [&](int tile, int half, int buf){
    const bf16* g = B + (size_t)(n0 + half*128 + srow)*K + tile*64 + scol;
    bf16* l = &Bsm[buf][half*128*64 + wave*8*64];
    gload_lds16(g, l);
    gload_lds16(g + (size_t)64*K, l + 64*64);
  };
  auto rdA = [&](int buf, int fi, int ks)->bf16x8_t{
    return *(const bf16x8_t*)&Asm[buf][(wm*128 + fi*16 + lrow)*64 + ((((ks)*4 + quad) ^ (lrow & 7)) << 3)];
  };
  auto rdB = [&](int buf, int j, int ks)->bf16x8_t{
    return *(const bf16x8_t*)&Bsm[buf][(wn*64 + j*16 + lrow)*64 + ((((ks)*4 + quad) ^ (lrow & 7)) << 3)];
  };

  f32x4_t acc[8][4];
  #pragma unroll
  for (int i=0;i<8;i++)
    #pragma unroll
    for (int j=0;j<4;j++) acc[i][j] = (f32x4_t){0.f,0.f,0.f,0.f};
  bf16x8_t b00,b01,b10,b11,b20,b21,b30,b31;

  const int nt    = K >> 6;    // K-tiles of 64
  const int nIter = nt >> 1;   // 2 tiles / iteration

  stageB(0, 0, 0); stageB(0, 1, 0);
  stageA(0, 0, 0); stageA(0, 1, 0);
  stageB(1, 0, 1); stageB(1, 1, 1);
  asm volatile("s_waitcnt vmcnt(4)" ::: "memory");
  __builtin_amdgcn_s_barrier();

  for (int it = 0; it < nIter; ++it){
    const int t1 = 2*it + 1, t2 = 2*it + 2, t3 = 2*it + 3;
    const bool ok2 = (t2 < nt), ok3 = (t3 < nt);
    GPHASE(0, 0, stageA(t1, 0, 1), );
    GPHASE(0, 1, stageA(t1, 1, 1), );
    GPHASE(0, 2, if (ok2) stageB(t2, 0, 0), );
    GPHASE(0, 3, if (ok2) stageB(t2, 1, 0), WAIT_STEADY);
    GPHASE(1, 0, if (ok2) stageA(t2, 0, 0), );
    GPHASE(1, 1, if (ok2) stageA(t2, 1, 0), );
    GPHASE(1, 2, if (ok3) stageB(t3, 0, 1), );
    GPHASE(1, 3, if (ok3) stageB(t3, 1, 1), WAIT_STEADY);
  }

  // ---- epilogue: LDS-staged coalesced C stores, padded rows ----
  constexpr int ROWP = 256 + 16/(int)sizeof(OutT);     // fp32: 260, bf16: 264 (stride in OutT)
  OutT* tile = (OutT*)&Asm[0][0];
  const int trow = t >> 4;                             // 0..31
  const int tcol = (t & 15) * 16;                      // 16 OutT per thread per step
  float bvj[4];
  #pragma unroll
  for (int j=0;j<4;j++) bvj[j] = HB ? bias[n0 + wn*64 + j*16 + lrow] : 0.f;
  const int grow = m0 + (trow >> 4)*128 + (trow & 15);   // + i*16 per step

  int cbase = 0;
  float c1v[8];
  if constexpr (FUSE){
    cbase = (n0 + tcol) >> 1;                          // 8 channels per thread segment
    f32x4_t c1a = *(const f32x4_t*)(c1buf + cbase);
    f32x4_t c1b = *(const f32x4_t*)(c1buf + cbase + 4);
    #pragma unroll
    for (int k=0;k<4;k++){ c1v[k] = c1a[k]; c1v[4+k] = c1b[k]; }
  }

  #pragma unroll
  for (int i=0;i<8;i++){
    __builtin_amdgcn_s_barrier();                 // prev step's LDS reads done
    #pragma unroll
    for (int j=0;j<4;j++){
      int lcol = wn*64 + j*16 + lrow;
      #pragma unroll
      for (int r=0;r<4;r++)
        store_cvt(&tile[(wm*16 + quad*4 + r)*ROWP + lcol], acc[i][j][r] + bvj[j]);
    }
    __builtin_amdgcn_s_barrier();                 // writes visible
    const int4* lp = (const int4*)&tile[trow*ROWP + tcol];
    if constexpr (FUSE){
      // 16 bf16 logits = 8 (zr,zi) pairs for channels cbase..cbase+7 at row grow+i*16
      int4 w0 = lp[0], w1 = lp[1];
      unsigned int lw[8] = {(unsigned)w0.x,(unsigned)w0.y,(unsigned)w0.z,(unsigned)w0.w,
                            (unsigned)w1.x,(unsigned)w1.y,(unsigned)w1.z,(unsigned)w1.w};
      const int row = grow + i*16;
      uint4 xv4 = *(const uint4*)(xv_src + (size_t)row*D + cbase);    // 8 bf16 x_conv
      float xv[8];
      bf16x2_unpack(xv4.x, xv[0], xv[1]); bf16x2_unpack(xv4.y, xv[2], xv[3]);
      bf16x2_unpack(xv4.z, xv[4], xv[5]); bf16x2_unpack(xv4.w, xv[6], xv[7]);
      unsigned int out[8];
      #pragma unroll
      for (int k=0;k<8;k++){
        float zr, zi;
        bf16x2_unpack(lw[k], zr, zi);
        float a  = __expf(c1v[k] * sigmoid_f(zr));
        float bt = sqrtf(fmaxf(1.f - a*a, 1e-6f)) * sigmoid_f(zi) * xv[k];
        out[k] = bf16x2_pack(1.f - a, bt);       // (d, b_t)
      }
      int4* gp = (int4*)&C[(size_t)row*N + n0 + tcol];
      gp[0] = make_int4(out[0],out[1],out[2],out[3]);
      gp[1] = make_int4(out[4],out[5],out[6],out[7]);
    } else {
      int4* gp = (int4*)&C[(size_t)(grow + i*16)*N + n0 + tcol];
      #pragma unroll
      for (int q=0; q<(int)sizeof(OutT); ++q) gp[q] = lp[q];   // fp32: 4x16B, bf16: 2x16B
    }
  }
}

// ---------------- scan pass 1: segment-local (Aprod, Hend) from (d,bt) pairs ----------------
// ab row = 1024 uints: uint c = (d_c, bt_c).  AprodT/Hend stored [s][b*D+c].
__global__ __launch_bounds__(256) void scan1_k(const unsigned int* __restrict__ ab,
                                               float* __restrict__ AprodT, float* __restrict__ HendT){
  int idx = blockIdx.x*256 + threadIdx.x;       // (b, s, c4)
  int c4 = idx & 255;
  int c  = c4*4;
  int bs = idx >> 8;
  int s  = bs & (NSEG-1);
  int b  = bs >> 8;
  size_t m0 = (size_t)b*SEQL + (size_t)s*SEG;
  float A[4] = {1.f,1.f,1.f,1.f};
  float h[4] = {0.f,0.f,0.f,0.f};
  #pragma unroll 4
  for (int l=0; l<SEG; l++){
    uint4 u = *(const uint4*)(ab + (m0 + l)*1024 + 4*c4);
    unsigned int uu[4] = {u.x, u.y, u.z, u.w};
    #pragma unroll
    for (int j=0;j<4;j++){
      float dv, bt;
      bf16x2_unpack(uu[j], dv, bt);
      float a = 1.f - dv;
      A[j] *= a;
      h[j]  = fmaf(a, h[j], bt);
    }
  }
  size_t tbase = (size_t)s*NCHAIN + (size_t)b*D + c;
  *(f32x4_t*)(AprodT + tbase) = (f32x4_t){A[0],A[1],A[2],A[3]};
  *(f32x4_t*)(HendT  + tbase) = (f32x4_t){h[0],h[1],h[2],h[3]};
}

// ---------------- scan pass 2: cross-segment carry, wave-parallel ----------------
__global__ __launch_bounds__(256) void scan2_k(const float* __restrict__ AprodT, const float* __restrict__ HendT,
                                               float* __restrict__ carryT){
  int gid   = blockIdx.x*256 + threadIdx.x;
  int chain = gid >> 6;                       // 0..NCHAIN-1
  int lane  = gid & 63;
  int s0    = lane*4;
  float a[4], e[4];
  #pragma unroll
  for (int k=0;k<4;k++){
    a[k] = AprodT[(size_t)(s0+k)*NCHAIN + chain];
    e[k] = HendT [(size_t)(s0+k)*NCHAIN + chain];
  }
  float A = a[0], H = e[0];
  #pragma unroll
  for (int k=1;k<4;k++){ H = fmaf(a[k], H, e[k]); A *= a[k]; }
  #pragma unroll
  for (int off=1; off<64; off<<=1){
    float Ao = __shfl_up(A, off, 64);
    float Ho = __shfl_up(H, off, 64);
    if (lane >= off){ H = fmaf(A, Ho, H); A = A*Ao; }   // prev ∘ cur (H uses pre-update A)
  }
  float Hx = __shfl_up(H, 1, 64);           // exclusive prefix; initial h = 0
  if (lane == 0) Hx = 0.f;
  float h = Hx;
  #pragma unroll
  for (int k=0;k<4;k++){
    carryT[(size_t)(s0+k)*NCHAIN + chain] = h;
    h = fmaf(a[k], h, e[k]);
  }
}

// ---------------- scan pass 3: replay (d,bt) + carry, emit h over xcb (bf16x2) ----------------
__global__ __launch_bounds__(256) void scan3_k(const unsigned int* __restrict__ ab,
                                               unsigned int* __restrict__ hout,   // xcb region (dead), h bf16x2
                                               const float* __restrict__ carryT){
  int idx = blockIdx.x*256 + threadIdx.x;       // (b, s, c4)
  int c4 = idx & 255;
  int c  = c4*4;
  int bs = idx >> 8;
  int s  = bs & (NSEG-1);
  int b  = bs >> 8;
  size_t m0 = (size_t)b*SEQL + (size_t)s*SEG;
  f32x4_t h4 = *(const f32x4_t*)(carryT + (size_t)s*NCHAIN + (size_t)b*D + c);
  float h[4] = {h4[0], h4[1], h4[2], h4[3]};
  #pragma unroll 4
  for (int l=0; l<SEG; l++){
    size_t m = m0 + l;
    uint4 u = *(const uint4*)(ab + m*1024 + 4*c4);
    unsigned int uu[4] = {u.x, u.y, u.z, u.w};
    #pragma unroll
    for (int j=0;j<4;j++){
      float dv, bt;
      bf16x2_unpack(uu[j], dv, bt);
      h[j] = fmaf(1.f - dv, h[j], bt);
    }
    uint2 o;
    o.x = bf16x2_pack(h[0], h[1]);
    o.y = bf16x2_pack(h[2], h[3]);
    *(uint2*)(hout + m*512 + 2*c4) = o;
  }
}

// ---------------- RMSNorm: wave-per-row, 4 rows/block, in-place ----------------
__global__ __launch_bounds__(256) void rms_k(float* __restrict__ y, const float* __restrict__ nw){
  int wave = threadIdx.x >> 6, lane = threadIdx.x & 63;
  size_t row = (size_t)blockIdx.x*4 + wave;
  float* yr = y + row*D;
  f32x4_t v[4];
  #pragma unroll
  for (int q=0;q<4;q++) v[q] = *(const f32x4_t*)(yr + q*256 + lane*4);
  float ss = 0.f;
  #pragma unroll
  for (int q=0;q<4;q++) ss += v[q][0]*v[q][0] + v[q][1]*v[q][1] + v[q][2]*v[q][2] + v[q][3]*v[q][3];
  #pragma unroll
  for (int off=32; off>0; off>>=1) ss += __shfl_xor(ss, off, 64);
  float scale = rsqrtf(ss * (1.f/D) + 1e-6f);
  #pragma unroll
  for (int q=0;q<4;q++){
    f32x4_t w = *(const f32x4_t*)(nw + q*256 + lane*4);
    f32x4_t o;
    #pragma unroll
    for (int k=0;k<4;k++) o[k] = v[q][k]*scale*w[k];
    *(f32x4_t*)(yr + q*256 + lane*4) = o;
  }
}

extern "C" void kernel_launch(void* const* d_in, const int* in_sizes, int n_in,
                              void* d_out, int out_size, void* d_ws, size_t ws_size,
                              hipStream_t stream) {
  const float* x     = (const float*)d_in[0];
  const float* convw = (const float*)d_in[1];
  const float* convb = (const float*)d_in[2];
  const float* Wr_w  = (const float*)d_in[3];
  const float* Wr_b  = (const float*)d_in[4];
  const float* Wi_w  = (const float*)d_in[5];
  const float* Wi_b  = (const float*)d_in[6];
  const float* log_a = (const float*)d_in[7];
  const float* out_w = (const float*)d_in[8];
  const float* norm_w= (const float*)d_in[9];

  char* ws = (char*)d_ws;
  size_t off = 0;
  auto alloc = [&](size_t bytes)->char*{ char* p = ws + off; off += (bytes + 255) & ~(size_t)255; return p; };

  bf16*  xcb   = (bf16*) alloc((size_t)MROWS*D*2);       // 64 MB, x_conv; scan3 overwrites with h
  bf16*  ab    = (bf16*) alloc((size_t)MROWS*2*D*2);     // 128 MB, (d,bt) pairs from fused GEMM1
  bf16*  W1    = (bf16*) alloc((size_t)2*D*D*2);         // 4 MB (interleaved rows)
  bf16*  Wob   = (bf16*) alloc((size_t)D*D*2);           // 2 MB
  float* b1    = (float*)alloc((size_t)2*D*4);
  float* c1buf = (float*)alloc((size_t)D*4);
  float* AprodT= (float*)alloc((size_t)NSEG*NCHAIN*4);   // 4 MB, [s][chain]
  float* HendT = (float*)alloc((size_t)NSEG*NCHAIN*4);   // 4 MB
  float* carryT= (float*)alloc((size_t)NSEG*NCHAIN*4);   // 4 MB
  float* y     = (float*)d_out;                          // GEMM2 output, rmsnorm in-place

  // 1. weight prep (interleaved W1/b1, c1 table)
  prep_k<<<dim3((3*D*D + 255)/256), dim3(256), 0, stream>>>(Wr_w, Wi_w, Wr_b, Wi_b, out_w, log_a, W1, Wob, b1, c1buf);
  // 2. conv -> bf16 (4 ch x 2 rows / thread)
  conv_k<<<dim3((MROWS/2)*(D/4)/256), dim3(256), 0, stream>>>(x, convw, convb, (unsigned int*)xcb);
  // 3. GEMM1 fused: logits -> (d = 1-a_t, b_t) bf16 pairs, N=2048
  gemm256<bf16, true, true><<<dim3((MROWS/256)*((2*D)/256)), dim3(512), 0, stream>>>(xcb, W1, b1, ab, MROWS, 2*D, D, xcb, c1buf);
  // 4-6. blocked scan (SEG=32; pure fma recurrences)
  scan1_k<<<dim3(BATCH*NSEG*(D/4)/256), dim3(256), 0, stream>>>((const unsigned int*)ab, AprodT, HendT);
  scan2_k<<<dim3(NCHAIN*64/256), dim3(256), 0, stream>>>(AprodT, HendT, carryT);
  scan3_k<<<dim3(BATCH*NSEG*(D/4)/256), dim3(256), 0, stream>>>((const unsigned int*)ab, (unsigned int*)xcb, carryT);
  // 7. GEMM2: y = h @ out_w^T (fp32 out, no bias); A = h written over xcb
  gemm256<float, false, false><<<dim3((MROWS/256)*(D/256)), dim3(512), 0, stream>>>(xcb, Wob, nullptr, y, MROWS, D, D, nullptr, nullptr);
  // 8. RMSNorm in-place on d_out (wave per row)
  rms_k<<<dim3(MROWS/4), dim3(256), 0, stream>>>(y, norm_w);
}